// Round 1
// baseline (193.246 us; speedup 1.0000x reference)
//
#include <hip/hip_runtime.h>
#include <math.h>

// Rolling stats: W=64 window over (N=262144, F=32) fp32, stride 1, VALID.
// Out row t (t < N-63): [mean(32) | std(32) | min(32) | max(32) | sum(32)].
//
// Per-thread: column c + chunk of R=32 output rows.
//  Pass 1 (reverse, rows t0..t0+63): suffix min/max stored in register
//    arrays (unrolled), running sum/sumsq of first window.
//  Pass 2 (forward): O(1) prefix min/max over next rows + sliding sum/sumsq
//    (reload subtracted element -> L1 hit). window = op(suffix[j], prefix).
// Lanes 0..31 = 32 columns of one chunk -> all loads/stores are aligned
// 128B segments (output row stride 640B = 5*128B).

#define WINW 64
#define RCH 32
#define NF 32

__global__ __launch_bounds__(256) void rolling_stats_kernel(
    const float* __restrict__ x, float* __restrict__ out, int N, int T_out) {
  int tid = blockIdx.x * blockDim.x + threadIdx.x;
  int c = tid & (NF - 1);
  int chunk = tid >> 5;
  int nchunk = (T_out + RCH - 1) / RCH;
  if (chunk >= nchunk) return;
  int t0 = chunk * RCH;

  const float* xc = x + c;

  float smin[RCH], smax[RCH];
  float ssum = 0.f, ssq = 0.f;
  float rmin = INFINITY, rmax = -INFINITY;

  // Pass 1: reverse scan over the first window [t0, t0+63].
  // All rows in-bounds: t0 <= T_out-1 = N-64  =>  t0+63 <= N-1.
#pragma unroll
  for (int j = WINW - 1; j >= 0; --j) {
    float a = xc[(size_t)(t0 + j) * NF];
    rmin = fminf(rmin, a);
    rmax = fmaxf(rmax, a);
    ssum += a;
    ssq = fmaf(a, a, ssq);
    if (j < RCH) {  // constant after unroll; only first RCH suffixes needed
      smin[j] = rmin;
      smax[j] = rmax;
    }
  }

  // Pass 2: forward over the chunk's outputs.
  float pmin = INFINITY, pmax = -INFINITY;
  float wsum = ssum, wsq = ssq;
  float* oc = out + c;
#pragma unroll
  for (int j = 0; j < RCH; ++j) {
    if (j > 0) {
      int rnew = t0 + (WINW - 1) + j;      // incoming row t0+63+j
      rnew = rnew < N ? rnew : N - 1;      // clamp (tail chunk; output guarded)
      float b = xc[(size_t)rnew * NF];
      float a = xc[(size_t)(t0 + j - 1) * NF];  // outgoing row (L1 hit)
      pmin = fminf(pmin, b);
      pmax = fmaxf(pmax, b);
      wsum += b - a;
      wsq = fmaf(b, b, wsq);
      wsq = fmaf(-a, a, wsq);
    }
    int t = t0 + j;
    if (t < T_out) {
      float wmin = fminf(smin[j], pmin);
      float wmax = fmaxf(smax[j], pmax);
      float mean = wsum * 0.015625f;                      // /64
      float var = fmaf(-mean, mean, wsq * 0.015625f);     // E[x^2]-E[x]^2
      var = fmaxf(var, 0.f);
      float sd = sqrtf(var);
      float* o = oc + (size_t)t * (5 * NF);
      o[0 * NF] = mean;
      o[1 * NF] = sd;
      o[2 * NF] = wmin;
      o[3 * NF] = wmax;
      o[4 * NF] = wsum;
    }
  }
}

extern "C" void kernel_launch(void* const* d_in, const int* in_sizes, int n_in,
                              void* d_out, int out_size, void* d_ws,
                              size_t ws_size, hipStream_t stream) {
  const float* x = (const float*)d_in[0];
  float* out = (float*)d_out;
  int N = in_sizes[0] / NF;   // 262144 rows
  int T_out = N - (WINW - 1); // 262081 output rows
  int nchunk = (T_out + RCH - 1) / RCH;
  int nthreads = nchunk * NF;
  int nblocks = (nthreads + 255) / 256;
  rolling_stats_kernel<<<nblocks, 256, 0, stream>>>(x, out, N, T_out);
}